// Round 1
// baseline (975.157 us; speedup 1.0000x reference)
//
#include <hip/hip_runtime.h>

#define B_ 4096
#define T_ 512
#define H_ 10
#define L_ 5
#define G_ 6   // batch elements per wave (10 lanes each, 60/64 lanes used)

__device__ __forceinline__ float sigm(float x) {
    return __builtin_amdgcn_rcpf(1.0f + __expf(-x));
}
__device__ __forceinline__ float tanh_(float x) {
    // 1 - 2/(e^{2x}+1); saturates correctly at +/-1 for large |x|
    return 1.0f - 2.0f * __builtin_amdgcn_rcpf(__expf(2.0f * x) + 1.0f);
}

// Block = 320 threads = 5 waves; wave l handles layer l for 6 batch elements.
// Software-pipelined over time with skew: wave l at step s computes t = s - l.
// Hidden-state flow (inter-layer AND own-layer recurrent) via double-buffered LDS.
// Lane j of each 10-lane group owns hidden unit j: computes gate rows j,10+j,20+j,30+j,
// so the c/h update is lane-local; only the h-vector broadcast goes through LDS.
__global__ __launch_bounds__(320)
void lstm5(const float* __restrict__ x,     // [B, T, 2]
           const float* __restrict__ h0,    // [L, B, H]
           const float* __restrict__ c0,    // [L, B, H]
           const float* __restrict__ Wih0,  // [40, 2]
           const float* __restrict__ WihR,  // [4, 40, 10]
           const float* __restrict__ Whh,   // [5, 40, 10]
           const float* __restrict__ bias,  // [5, 40]
           const float* __restrict__ Wf,    // [10]
           const float* __restrict__ bfp,   // [1]
           float* __restrict__ out)         // [B*T] ++ [L*B*H] (hT) ++ [L*B*H] (cT)
{
    // pad inner dim to 12 floats: group bases hit disjoint bank quads (g*12 mod 32)
    __shared__ __align__(16) float hbuf[L_][2][G_][12];

    const int tid  = threadIdx.x;
    const int l    = tid >> 6;        // wave id == layer
    const int lane = tid & 63;
    const int g    = lane / 10;       // batch slot within wave (6..: idle)
    const int j    = lane - g * 10;   // hidden unit owned by this lane
    const int batch = blockIdx.x * G_ + g;
    const bool act = (g < G_) && (batch < B_);
    const int  cb  = act ? batch : 0;

    // ---- hoist weights into registers (row set depends only on l, j) ----
    float wih[4][10], whh[4][10], bs[4], wf[10];
    #pragma unroll
    for (int q = 0; q < 4; ++q) {
        const int row = q * H_ + j;
        bs[q] = bias[l * 40 + row];
        #pragma unroll
        for (int k = 0; k < 10; ++k)
            whh[q][k] = Whh[l * 400 + row * 10 + k];
        if (l == 0) {
            wih[q][0] = Wih0[row * 2 + 0];
            wih[q][1] = Wih0[row * 2 + 1];
            #pragma unroll
            for (int k = 2; k < 10; ++k) wih[q][k] = 0.0f;
        } else {
            #pragma unroll
            for (int k = 0; k < 10; ++k)
                wih[q][k] = WihR[(l - 1) * 400 + row * 10 + k];
        }
    }
    #pragma unroll
    for (int k = 0; k < 10; ++k) wf[k] = Wf[k];
    const float bf = bfp[0];

    // ---- initial state ----
    float c = 0.0f;
    if (act) c = c0[l * (B_ * H_) + cb * H_ + j];
    // preload h0 into the parity the first own-h read (step s=l, parity (l+1)&1) uses
    if (act) hbuf[l][(l + 1) & 1][g][j] = h0[l * (B_ * H_) + cb * H_ + j];

    float2 xc = make_float2(0.0f, 0.0f);
    if (l == 0 && act) xc = *(const float2*)(x + (size_t)cb * (T_ * 2));

    __syncthreads();

    for (int s = 0; s < T_ + L_; ++s) {   // 517 steps
        const int t  = s - l;
        const int pr = (s + 1) & 1;       // read parity  == (s-1)&1
        const int pw = s & 1;             // write parity
        const bool do_rec  = act && (t >= 0) && (t < T_);
        const bool do_proj = (l == 4) && act && (s >= 5);   // tp = s-5 in [0,512)

        float hown[10];
        if (do_rec || do_proj) {
            const float4* hp = (const float4*)&hbuf[l][pr][g][0];
            float4 a = hp[0];
            float4 b = hp[1];
            float2 cpair = *(const float2*)&hbuf[l][pr][g][8];
            hown[0]=a.x; hown[1]=a.y; hown[2]=a.z; hown[3]=a.w;
            hown[4]=b.x; hown[5]=b.y; hown[6]=b.z; hown[7]=b.w;
            hown[8]=cpair.x; hown[9]=cpair.y;
        }

        if (do_rec) {
            float a0 = bs[0], a1 = bs[1], a2 = bs[2], a3 = bs[3];
            float2 xn = xc;
            if (l == 0) {
                if (t + 1 < T_)   // prefetch next step's x, latency hidden under gates
                    xn = *(const float2*)(x + (size_t)cb * (T_ * 2) + (t + 1) * 2);
                a0 += wih[0][0]*xc.x + wih[0][1]*xc.y;
                a1 += wih[1][0]*xc.x + wih[1][1]*xc.y;
                a2 += wih[2][0]*xc.x + wih[2][1]*xc.y;
                a3 += wih[3][0]*xc.x + wih[3][1]*xc.y;
            } else {
                const float4* xp = (const float4*)&hbuf[l - 1][pr][g][0];
                float4 a = xp[0];
                float4 b = xp[1];
                float2 cpair = *(const float2*)&hbuf[l - 1][pr][g][8];
                float xin[10];
                xin[0]=a.x; xin[1]=a.y; xin[2]=a.z; xin[3]=a.w;
                xin[4]=b.x; xin[5]=b.y; xin[6]=b.z; xin[7]=b.w;
                xin[8]=cpair.x; xin[9]=cpair.y;
                #pragma unroll
                for (int k = 0; k < 10; ++k) {
                    a0 += wih[0][k] * xin[k];
                    a1 += wih[1][k] * xin[k];
                    a2 += wih[2][k] * xin[k];
                    a3 += wih[3][k] * xin[k];
                }
            }
            #pragma unroll
            for (int k = 0; k < 10; ++k) {
                a0 += whh[0][k] * hown[k];
                a1 += whh[1][k] * hown[k];
                a2 += whh[2][k] * hown[k];
                a3 += whh[3][k] * hown[k];
            }
            const float ig = sigm(a0);
            const float fg = sigm(a1);
            const float gg = tanh_(a2);
            const float og = sigm(a3);
            c = fg * c + ig * gg;
            const float hn = og * tanh_(c);
            hbuf[l][pw][g][j] = hn;
            if (t == T_ - 1) {
                out[(size_t)(B_ * T_) + l * (B_ * H_) + cb * H_ + j] = hn;
                out[(size_t)(B_ * T_) + (size_t)(L_ * B_ * H_) + l * (B_ * H_) + cb * H_ + j] = c;
            }
            xc = xn;
        }

        if (do_proj) {
            const int tp = s - 5;
            float v = bf;
            #pragma unroll
            for (int k = 0; k < 10; ++k) v += wf[k] * hown[k];
            const float ov = sigm(v);
            if (j == 0) out[(size_t)cb * T_ + tp] = ov;
        }

        __syncthreads();
    }
}

extern "C" void kernel_launch(void* const* d_in, const int* in_sizes, int n_in,
                              void* d_out, int out_size, void* d_ws, size_t ws_size,
                              hipStream_t stream) {
    const float* x    = (const float*)d_in[0];
    const float* h0   = (const float*)d_in[1];
    const float* c0   = (const float*)d_in[2];
    const float* Wih0 = (const float*)d_in[3];
    const float* WihR = (const float*)d_in[4];
    const float* Whh  = (const float*)d_in[5];
    const float* bias = (const float*)d_in[6];
    const float* Wf   = (const float*)d_in[7];
    const float* bf   = (const float*)d_in[8];
    float* out = (float*)d_out;

    dim3 grid((B_ + G_ - 1) / G_);   // 683 blocks
    dim3 block(320);                 // 5 waves = 5 layers
    hipLaunchKernelGGL(lstm5, grid, block, 0, stream,
                       x, h0, c0, Wih0, WihR, Whh, bias, Wf, bf, out);
}

// Round 2
// 569.405 us; speedup vs baseline: 1.7126x; 1.7126x over previous
//
#include <hip/hip_runtime.h>

#define B_ 4096
#define T_ 512
#define H_ 10
#define L_ 5
#define G_ 6                    // batch elements per wave (10 lanes each)
#define C_ 8                    // timesteps per chunk (one barrier per chunk)
#define NCH (T_ / C_)           // 64 chunks per layer
#define NSTEP (NCH + L_ - 1)    // 68 supersteps (5-deep layer pipeline)
#define PSTR (C_ * G_ * 12)     // floats between parity slabs   (576)
#define TSTR (G_ * 12)          // floats between timestep slots (72)

#define LOG2E 1.44269504f

__device__ __forceinline__ float sigm2(float xs) {   // xs pre-scaled by log2e
    return __builtin_amdgcn_rcpf(1.0f + __builtin_amdgcn_exp2f(-xs));
}
__device__ __forceinline__ float tanh2(float xs) {   // xs pre-scaled by 2*log2e
    return fmaf(-2.0f, __builtin_amdgcn_rcpf(__builtin_amdgcn_exp2f(xs) + 1.0f), 1.0f);
}

#define DOT10(acc, W, A, Bv, Cv)                              \
    acc = fmaf(W[0], A.x,  acc); acc = fmaf(W[1], A.y,  acc); \
    acc = fmaf(W[2], A.z,  acc); acc = fmaf(W[3], A.w,  acc); \
    acc = fmaf(W[4], Bv.x, acc); acc = fmaf(W[5], Bv.y, acc); \
    acc = fmaf(W[6], Bv.z, acc); acc = fmaf(W[7], Bv.w, acc); \
    acc = fmaf(W[8], Cv.x, acc); acc = fmaf(W[9], Cv.y, acc);

// Block = 5 waves = 5 layers, software-pipelined over time in chunks of C_ steps.
// Wave l at superstep S processes chunk q = S - l (timesteps q*C_ .. +C_-1).
// Cross-layer handoff: double-buffered chunk slab in LDS, 1 barrier per superstep.
// Own-layer recurrence: same-wave LDS write->read (lgkmcnt only, no barrier).
// Lane j of each 10-lane group owns hidden unit j (gate rows j,10+j,20+j,30+j),
// so c/h updates are lane-local; weights live in VGPRs, pre-scaled for exp2.
__global__ __launch_bounds__(320, 4)
void lstm5(const float* __restrict__ x,     // [B, T, 2]
           const float* __restrict__ h0,    // [L, B, H]
           const float* __restrict__ c0,    // [L, B, H]
           const float* __restrict__ Wih0,  // [40, 2]
           const float* __restrict__ WihR,  // [4, 40, 10]
           const float* __restrict__ Whh,   // [5, 40, 10]
           const float* __restrict__ bias,  // [5, 40]
           const float* __restrict__ Wf,    // [10]
           const float* __restrict__ bfp,   // [1]
           float* __restrict__ out)         // [B*T] ++ [L*B*H] ++ [L*B*H]
{
    __shared__ __align__(16) float buf[L_][2][C_][G_][12];

    const int tid  = threadIdx.x;
    const int l    = tid >> 6;
    const int lane = tid & 63;
    const int g    = lane / 10;
    const int j    = lane - g * 10;
    const int batch = blockIdx.x * G_ + g;
    const bool act = (g < G_) && (batch < B_);
    const int  cb  = act ? batch : 0;

    const float scq[4] = {LOG2E, LOG2E, 2.0f * LOG2E, LOG2E};

    // ---- weights -> VGPRs, pre-scaled so activations use exp2 directly ----
    float wih[4][10], whh[4][10], bs[4];
    #pragma unroll
    for (int q = 0; q < 4; ++q) {
        const int row = q * H_ + j;
        const float sc = scq[q];
        bs[q] = bias[l * 40 + row] * sc;
        #pragma unroll
        for (int k = 0; k < 10; ++k)
            whh[q][k] = Whh[l * 400 + row * 10 + k] * sc;
        if (l == 0) {
            wih[q][0] = Wih0[row * 2 + 0] * sc;   // layer0 path only uses [0..1]
            wih[q][1] = Wih0[row * 2 + 1] * sc;
        } else {
            #pragma unroll
            for (int k = 0; k < 10; ++k)
                wih[q][k] = WihR[(l - 1) * 400 + row * 10 + k] * sc;
        }
    }
    // projection weights are lane-invariant -> SGPRs
    float wfs[10], bfs = 0.0f;
    if (l == 4) {
        #pragma unroll
        for (int k = 0; k < 10; ++k)
            wfs[k] = __uint_as_float(__builtin_amdgcn_readfirstlane(
                         __float_as_uint(Wf[k] * LOG2E)));
        bfs = __uint_as_float(__builtin_amdgcn_readfirstlane(
                         __float_as_uint(bfp[0] * LOG2E)));
    }

    // ---- initial state ----
    float c = 0.0f;
    if (act) {
        c = c0[l * (B_ * H_) + cb * H_ + j];
        // preload h0 into the slot the first own-read (S=l, tc=0) consumes
        buf[l][(l + 1) & 1][C_ - 1][g][j] = h0[l * (B_ * H_) + cb * H_ + j];
    }
    __syncthreads();

    float* bl = &buf[l][0][0][0][0] + g * 12;
    const float* bp = (l > 0) ? (&buf[l - 1][0][0][0][0] + g * 12) : bl;
    const float* xg = x + (size_t)cb * (T_ * 2);

    for (int S = 0; S < NSTEP; ++S) {
        const int q  = S - l;
        const int pw = S & 1;
        float*       wr  = bl + pw * PSTR;          // this superstep's writes
        const float* rdo = bl + (1 - pw) * PSTR;    // own prev-chunk slab
        const float* rdp = bp + (1 - pw) * PSTR;    // prev-layer slab (chunk q)

        if (act && (unsigned)q < (unsigned)NCH) {
            if (l == 0) {
                #pragma unroll
                for (int tc = 0; tc < C_; ++tc) {
                    const int t = q * C_ + tc;
                    const float2 xt = *(const float2*)(xg + t * 2);
                    const float* ho = (tc == 0) ? (rdo + (C_ - 1) * TSTR)
                                                : (wr + (tc - 1) * TSTR);
                    float4 hA = *(const float4*)(ho);
                    float4 hB = *(const float4*)(ho + 4);
                    float2 hC = *(const float2*)(ho + 8);
                    float a0 = fmaf(wih[0][0], xt.x, fmaf(wih[0][1], xt.y, bs[0]));
                    float a1 = fmaf(wih[1][0], xt.x, fmaf(wih[1][1], xt.y, bs[1]));
                    float a2 = fmaf(wih[2][0], xt.x, fmaf(wih[2][1], xt.y, bs[2]));
                    float a3 = fmaf(wih[3][0], xt.x, fmaf(wih[3][1], xt.y, bs[3]));
                    DOT10(a0, whh[0], hA, hB, hC)
                    DOT10(a1, whh[1], hA, hB, hC)
                    DOT10(a2, whh[2], hA, hB, hC)
                    DOT10(a3, whh[3], hA, hB, hC)
                    const float ig = sigm2(a0), fg = sigm2(a1);
                    const float gg = tanh2(a2), og = sigm2(a3);
                    c = fmaf(fg, c, ig * gg);
                    const float hn = og * tanh2(2.0f * LOG2E * c);
                    wr[tc * TSTR + j] = hn;
                    if (q == NCH - 1 && tc == C_ - 1) {
                        out[(size_t)(B_ * T_) + l * (B_ * H_) + cb * H_ + j] = hn;
                        out[(size_t)(B_ * T_) + (size_t)(L_ * B_ * H_)
                            + l * (B_ * H_) + cb * H_ + j] = c;
                    }
                }
            } else {
                #pragma unroll
                for (int tc = 0; tc < C_; ++tc) {
                    const float* xi = rdp + tc * TSTR;
                    float4 xA = *(const float4*)(xi);
                    float4 xB = *(const float4*)(xi + 4);
                    float2 xC = *(const float2*)(xi + 8);
                    const float* ho = (tc == 0) ? (rdo + (C_ - 1) * TSTR)
                                                : (wr + (tc - 1) * TSTR);
                    float4 hA = *(const float4*)(ho);
                    float4 hB = *(const float4*)(ho + 4);
                    float2 hC = *(const float2*)(ho + 8);
                    float a0 = bs[0], a1 = bs[1], a2 = bs[2], a3 = bs[3];
                    DOT10(a0, wih[0], xA, xB, xC)
                    DOT10(a1, wih[1], xA, xB, xC)
                    DOT10(a2, wih[2], xA, xB, xC)
                    DOT10(a3, wih[3], xA, xB, xC)
                    DOT10(a0, whh[0], hA, hB, hC)
                    DOT10(a1, whh[1], hA, hB, hC)
                    DOT10(a2, whh[2], hA, hB, hC)
                    DOT10(a3, whh[3], hA, hB, hC)
                    const float ig = sigm2(a0), fg = sigm2(a1);
                    const float gg = tanh2(a2), og = sigm2(a3);
                    c = fmaf(fg, c, ig * gg);
                    const float hn = og * tanh2(2.0f * LOG2E * c);
                    wr[tc * TSTR + j] = hn;
                    if (q == NCH - 1 && tc == C_ - 1) {
                        out[(size_t)(B_ * T_) + l * (B_ * H_) + cb * H_ + j] = hn;
                        out[(size_t)(B_ * T_) + (size_t)(L_ * B_ * H_)
                            + l * (B_ * H_) + cb * H_ + j] = c;
                    }
                    if (l == 4) {
                        // project h_{t-1} (the own-vector just read), 1 step delayed
                        if (q > 0 || tc > 0) {
                            float v = bfs;
                            v = fmaf(wfs[0], hA.x, v); v = fmaf(wfs[1], hA.y, v);
                            v = fmaf(wfs[2], hA.z, v); v = fmaf(wfs[3], hA.w, v);
                            v = fmaf(wfs[4], hB.x, v); v = fmaf(wfs[5], hB.y, v);
                            v = fmaf(wfs[6], hB.z, v); v = fmaf(wfs[7], hB.w, v);
                            v = fmaf(wfs[8], hC.x, v); v = fmaf(wfs[9], hC.y, v);
                            const float ov = sigm2(v);
                            if (j == 0) out[(size_t)cb * T_ + (q * C_ + tc - 1)] = ov;
                        }
                    }
                }
            }
        }
        __syncthreads();
    }

    // epilogue: projection for t = T-1 (h written by wave 4 itself at S=67, pw=1)
    if (l == 4 && act) {
        const float* ho = bl + 1 * PSTR + (C_ - 1) * TSTR;
        float4 hA = *(const float4*)(ho);
        float4 hB = *(const float4*)(ho + 4);
        float2 hC = *(const float2*)(ho + 8);
        float v = bfs;
        v = fmaf(wfs[0], hA.x, v); v = fmaf(wfs[1], hA.y, v);
        v = fmaf(wfs[2], hA.z, v); v = fmaf(wfs[3], hA.w, v);
        v = fmaf(wfs[4], hB.x, v); v = fmaf(wfs[5], hB.y, v);
        v = fmaf(wfs[6], hB.z, v); v = fmaf(wfs[7], hB.w, v);
        v = fmaf(wfs[8], hC.x, v); v = fmaf(wfs[9], hC.y, v);
        if (j == 0) out[(size_t)cb * T_ + (T_ - 1)] = sigm2(v);
    }
}

extern "C" void kernel_launch(void* const* d_in, const int* in_sizes, int n_in,
                              void* d_out, int out_size, void* d_ws, size_t ws_size,
                              hipStream_t stream) {
    const float* x    = (const float*)d_in[0];
    const float* h0   = (const float*)d_in[1];
    const float* c0   = (const float*)d_in[2];
    const float* Wih0 = (const float*)d_in[3];
    const float* WihR = (const float*)d_in[4];
    const float* Whh  = (const float*)d_in[5];
    const float* bias = (const float*)d_in[6];
    const float* Wf   = (const float*)d_in[7];
    const float* bf   = (const float*)d_in[8];
    float* out = (float*)d_out;

    dim3 grid((B_ + G_ - 1) / G_);   // 683 blocks
    dim3 block(320);                 // 5 waves = 5 layers
    hipLaunchKernelGGL(lstm5, grid, block, 0, stream,
                       x, h0, c0, Wih0, WihR, Whh, bias, Wf, bf, out);
}

// Round 3
// 375.094 us; speedup vs baseline: 2.5998x; 1.5180x over previous
//
#include <hip/hip_runtime.h>

#define B_ 4096
#define T_ 512
#define H_ 10
#define L_ 5
#define LOG2E 1.44269504f

// LDS layout (floats):
//  [0..71]   6 h-slots x 12 floats (slots 0-4 = layer h, slot 5 = zeros)
//  [72..87]  trash (discarded writes)
//  [88..]    xbuf: 520 entries x 4 floats, entry t = [x0(t), x1(t), 0, 0]
#define SLOTF(g)   ((g) * 12)
#define TRASH_OFF  72
#define XBUF_OFF   88
#define XENT       520
#define LDS_FLOATS (XBUF_OFF + XENT * 4)

__device__ __forceinline__ float sigm2(float xs) {   // xs pre-scaled by log2e
    return __builtin_amdgcn_rcpf(1.0f + __builtin_amdgcn_exp2f(-xs));
}
__device__ __forceinline__ float tanh2(float xs) {   // xs pre-scaled by 2*log2e
    return fmaf(-2.0f, __builtin_amdgcn_rcpf(__builtin_amdgcn_exp2f(xs) + 1.0f), 1.0f);
}

#define DOT10(acc, W, A, Bv, Cv)                              \
    acc = fmaf(W[0], A.x,  acc); acc = fmaf(W[1], A.y,  acc); \
    acc = fmaf(W[2], A.z,  acc); acc = fmaf(W[3], A.w,  acc); \
    acc = fmaf(W[4], Bv.x, acc); acc = fmaf(W[5], Bv.y, acc); \
    acc = fmaf(W[6], Bv.z, acc); acc = fmaf(W[7], Bv.w, acc); \
    acc = fmaf(W[8], Cv.x, acc); acc = fmaf(W[9], Cv.y, acc);

// One iteration of the in-wave layer pipeline. GUARD: prologue/epilogue write
// guards. OUTST: emit the projection store (group 5's i-gate IS the output).
#define GATES(S, GUARD, OUTST)                                                 \
  {                                                                            \
    const float4 xA = *(const float4*)(prevp);                                 \
    const float4 xB = *(const float4*)(prevp + 4);                             \
    const float2 xC = *(const float2*)(prevp + 8);                             \
    const float4 hA = *(const float4*)(ownp);                                  \
    const float4 hB = *(const float4*)(ownp + 4);                              \
    const float2 hC = *(const float2*)(ownp + 8);                              \
    float a0 = bs4[0], a1 = bs4[1], a2 = bs4[2], a3 = bs4[3];                  \
    DOT10(a0, wih[0], xA, xB, xC)                                              \
    DOT10(a1, wih[1], xA, xB, xC)                                              \
    DOT10(a2, wih[2], xA, xB, xC)                                              \
    DOT10(a3, wih[3], xA, xB, xC)                                              \
    DOT10(a0, whh[0], hA, hB, hC)                                              \
    DOT10(a1, whh[1], hA, hB, hC)                                              \
    DOT10(a2, whh[2], hA, hB, hC)                                              \
    DOT10(a3, whh[3], hA, hB, hC)                                              \
    const float ig = sigm2(a0), fg = sigm2(a1);                                \
    const float gg = tanh2(a2), og = sigm2(a3);                                \
    const float cn = fmaf(fg, c, ig * gg);                                     \
    const float hn = og * tanh2(cn * (2.0f * LOG2E));                          \
    if (GUARD) {                                                               \
      const int tl = (S) - g;                                                  \
      const bool valid = (unsigned)tl < (unsigned)T_;                          \
      float* wrt = valid ? wrp : trashp;                                       \
      *wrt = hn;                                                               \
      if (valid) c = cn;                                                       \
      if ((g < 5) && (tl == T_ - 1)) {                                         \
        out[(size_t)(B_ * T_) + g * (B_ * H_) + b * H_ + j] = hn;              \
        out[(size_t)(B_ * T_) + (size_t)(L_ * B_ * H_)                         \
            + g * (B_ * H_) + b * H_ + j] = cn;                                \
      }                                                                        \
    } else {                                                                   \
      *wrp = hn;                                                               \
      c = cn;                                                                  \
    }                                                                          \
    if (OUTST) {                                                               \
      if (g == 5) out[(size_t)b * T_ + ((S) - 5)] = ig;                        \
    }                                                                          \
    prevp += pinc;                                                             \
  }

// One wave = one batch element, all 5 layers pipelined across lane-groups.
// Group g (lanes 10g..10g+9) = layer g; lane j owns hidden unit j (gate rows
// j,10+j,20+j,30+j). Group 5 computes the output projection via the uniform
// gate code (wih[0]=Wf, bs4[0]=bf, whh=0 -> its "i-gate" = sigmoid(Wf.h4+bf)).
// No __syncthreads in the main loop: same-wave DS ordering is sufficient.
__global__ __launch_bounds__(64, 3)
void lstm5(const float* __restrict__ x,     // [B, T, 2]
           const float* __restrict__ h0,    // [L, B, H]
           const float* __restrict__ c0,    // [L, B, H]
           const float* __restrict__ Wih0,  // [40, 2]
           const float* __restrict__ WihR,  // [4, 40, 10]
           const float* __restrict__ Whh,   // [5, 40, 10]
           const float* __restrict__ bias,  // [5, 40]
           const float* __restrict__ Wf,    // [10]
           const float* __restrict__ bfp,   // [1]
           float* __restrict__ out)         // [B*T] ++ [L*B*H] ++ [L*B*H]
{
    __shared__ __align__(16) float lds[LDS_FLOATS];

    const int lane = threadIdx.x;
    const int g = lane / 10;          // 0..6 (6 = lanes 60-63, idle)
    const int j = lane - g * 10;
    const int b = blockIdx.x;

    // ---- stage x[b] into LDS (16B-strided entries), zero pads & slot 5 ----
    {
        const float2* x2 = (const float2*)(x + (size_t)b * (T_ * 2));
        #pragma unroll
        for (int i = 0; i < 8; ++i) {
            const int idx = i * 64 + lane;
            float2 v = x2[idx];
            *(float4*)&lds[XBUF_OFF + idx * 4] = make_float4(v.x, v.y, 0.0f, 0.0f);
        }
        if (lane < 8)  lds[XBUF_OFF + 512 * 4 + lane] = 0.0f;  // entries 512-513
        if (lane < 12) lds[SLOTF(5) + lane] = 0.0f;            // zero slot
    }

    // ---- weights -> VGPRs (pre-scaled for exp2); group-dependent roles ----
    const float scq[4] = {LOG2E, LOG2E, 2.0f * LOG2E, LOG2E};
    float wih[4][10], whh[4][10], bs4[4];
    #pragma unroll
    for (int q = 0; q < 4; ++q) {
        bs4[q] = 0.0f;
        #pragma unroll
        for (int k = 0; k < 10; ++k) { wih[q][k] = 0.0f; whh[q][k] = 0.0f; }
    }
    if (g < 5) {
        #pragma unroll
        for (int q = 0; q < 4; ++q) {
            const int row = q * H_ + j;
            const float sc = scq[q];
            bs4[q] = bias[g * 40 + row] * sc;
            #pragma unroll
            for (int k = 0; k < 10; ++k)
                whh[q][k] = Whh[g * 400 + row * 10 + k] * sc;
            if (g == 0) {
                wih[q][0] = Wih0[row * 2 + 0] * sc;
                wih[q][1] = Wih0[row * 2 + 1] * sc;
            } else {
                #pragma unroll
                for (int k = 0; k < 10; ++k)
                    wih[q][k] = WihR[(g - 1) * 400 + row * 10 + k] * sc;
            }
        }
    } else if (g == 5) {
        #pragma unroll
        for (int k = 0; k < 10; ++k) wih[0][k] = Wf[k] * LOG2E;
        bs4[0] = bfp[0] * LOG2E;
    }

    // ---- initial state ----
    float c = 0.0f;
    if (g < 5) {
        c = c0[g * (B_ * H_) + b * H_ + j];
        lds[SLOTF(g) + j] = h0[g * (B_ * H_) + b * H_ + j];
    }
    __syncthreads();

    // ---- per-lane pointers ----
    float* ownp  = &lds[(g < 5) ? SLOTF(g) : SLOTF(5)];
    float* prevp = (g == 0) ? &lds[XBUF_OFF]
                 : (g <= 5) ? &lds[SLOTF(g - 1)]
                            : &lds[SLOTF(5)];
    float* wrp   = (g < 5) ? &lds[SLOTF(g) + j]
                           : &lds[TRASH_OFF + (lane - 50)];
    float* trashp = &lds[TRASH_OFF + (lane & 15)];
    const int pinc = (g == 0) ? 4 : 0;   // group 0 walks xbuf, 1 entry/iter

    // ---- pipeline: prologue (guarded) / steady / epilogue (guarded) ----
    for (int s = 0; s < 5; ++s)        GATES(s, true,  false)
    for (int s = 5; s <= 510; ++s)     GATES(s, false, true )
    for (int s = 511; s <= 516; ++s)   GATES(s, true,  true )
}

extern "C" void kernel_launch(void* const* d_in, const int* in_sizes, int n_in,
                              void* d_out, int out_size, void* d_ws, size_t ws_size,
                              hipStream_t stream) {
    const float* x    = (const float*)d_in[0];
    const float* h0   = (const float*)d_in[1];
    const float* c0   = (const float*)d_in[2];
    const float* Wih0 = (const float*)d_in[3];
    const float* WihR = (const float*)d_in[4];
    const float* Whh  = (const float*)d_in[5];
    const float* bias = (const float*)d_in[6];
    const float* Wf   = (const float*)d_in[7];
    const float* bf   = (const float*)d_in[8];
    float* out = (float*)d_out;

    dim3 grid(B_);     // one 1-wave block per batch element: perfect balance
    dim3 block(64);
    hipLaunchKernelGGL(lstm5, grid, block, 0, stream,
                       x, h0, c0, Wih0, WihR, Whh, bias, Wf, bf, out);
}

// Round 4
// 334.260 us; speedup vs baseline: 2.9174x; 1.1222x over previous
//
#include <hip/hip_runtime.h>

typedef float v2f __attribute__((ext_vector_type(2)));
typedef float v4f __attribute__((ext_vector_type(4)));

#define B_ 4096
#define T_ 512
#define H_ 10
#define L_ 5
#define LOG2E 1.44269504f

// LDS layout (floats). Slot stride 28 floats (112B): the 6 slot bases + trash
// land on 7 distinct bank quads (24*g%32 -> 0,28,24,20,16,12; trash=8).
#define SLOTF(g)   ((g) * 28)
#define TRASH_F    168                  // 32 floats
#define XBUF_F     200                  // 520 entries * 4 floats
#define LDS_FLOATS (XBUF_F + 520 * 4)   // 9120 B

__device__ __forceinline__ v2f pk_fma(v2f a, v2f b, v2f c) {
    v2f d;
    asm("v_pk_fma_f32 %0, %1, %2, %3" : "=v"(d) : "v"(a), "v"(b), "v"(c));
    return d;
}
__device__ __forceinline__ v2f pk_mul(v2f a, v2f b) {
    v2f d;
    asm("v_pk_mul_f32 %0, %1, %2" : "=v"(d) : "v"(a), "v"(b));
    return d;
}
__device__ __forceinline__ v2f pk_add(v2f a, v2f b) {
    v2f d;
    asm("v_pk_add_f32 %0, %1, %2" : "=v"(d) : "v"(a), "v"(b));
    return d;
}

__device__ __forceinline__ v2f sigm2p(v2f xs) {   // xs pre-scaled by log2e
    v2f r;
    r.x = __builtin_amdgcn_rcpf(1.0f + __builtin_amdgcn_exp2f(-xs.x));
    r.y = __builtin_amdgcn_rcpf(1.0f + __builtin_amdgcn_exp2f(-xs.y));
    return r;
}
__device__ __forceinline__ v2f tanh2p(v2f xs) {   // xs pre-scaled by 2*log2e
    v2f r;
    r.x = fmaf(-2.0f, __builtin_amdgcn_rcpf(__builtin_amdgcn_exp2f(xs.x) + 1.0f), 1.0f);
    r.y = fmaf(-2.0f, __builtin_amdgcn_rcpf(__builtin_amdgcn_exp2f(xs.y) + 1.0f), 1.0f);
    return r;
}

// 10-pair packed dot: input pairs from the five b128 loads (2 pairs each)
#define DOTX(acc, W)                                                  \
    acc = pk_fma(W[0], q0.lo, acc); acc = pk_fma(W[1], q0.hi, acc);   \
    acc = pk_fma(W[2], q1.lo, acc); acc = pk_fma(W[3], q1.hi, acc);   \
    acc = pk_fma(W[4], q2.lo, acc); acc = pk_fma(W[5], q2.hi, acc);   \
    acc = pk_fma(W[6], q3.lo, acc); acc = pk_fma(W[7], q3.hi, acc);   \
    acc = pk_fma(W[8], q4.lo, acc); acc = pk_fma(W[9], q4.hi, acc);
#define DOTH(acc, W)                                                  \
    acc = pk_fma(W[0], r0.lo, acc); acc = pk_fma(W[1], r0.hi, acc);   \
    acc = pk_fma(W[2], r1.lo, acc); acc = pk_fma(W[3], r1.hi, acc);   \
    acc = pk_fma(W[4], r2.lo, acc); acc = pk_fma(W[5], r2.hi, acc);   \
    acc = pk_fma(W[6], r3.lo, acc); acc = pk_fma(W[7], r3.hi, acc);   \
    acc = pk_fma(W[8], r4.lo, acc); acc = pk_fma(W[9], r4.hi, acc);

#define GATES(S, GUARD, OUTST)                                               \
  {                                                                          \
    const v4f q0 = *(const v4f*)(prevp);                                     \
    const v4f q1 = *(const v4f*)(prevp2);                                    \
    const v4f q2 = *(const v4f*)(prevp2 + 4);                                \
    const v4f q3 = *(const v4f*)(prevp2 + 8);                                \
    const v4f q4 = *(const v4f*)(prevp2 + 12);                               \
    const v4f r0 = *(const v4f*)(ownp);                                      \
    const v4f r1 = *(const v4f*)(ownp + 4);                                  \
    const v4f r2 = *(const v4f*)(ownp + 8);                                  \
    const v4f r3 = *(const v4f*)(ownp + 12);                                 \
    const v4f r4 = *(const v4f*)(ownp + 16);                                 \
    v2f a0 = bs2[0], a1 = bs2[1], a2 = bs2[2], a3 = bs2[3];                  \
    v2f h0a = zero2, h1a = zero2, h2a = zero2, h3a = zero2;                  \
    DOTX(a0, wih2[0]) DOTX(a1, wih2[1]) DOTX(a2, wih2[2]) DOTX(a3, wih2[3])  \
    DOTH(h0a, whh2[0]) DOTH(h1a, whh2[1])                                    \
    DOTH(h2a, whh2[2]) DOTH(h3a, whh2[3])                                    \
    a0 = pk_add(a0, h0a); a1 = pk_add(a1, h1a);                              \
    a2 = pk_add(a2, h2a); a3 = pk_add(a3, h3a);                              \
    const v2f ig = sigm2p(a0), fg = sigm2p(a1);                              \
    const v2f gg = tanh2p(a2), og = sigm2p(a3);                              \
    const v2f cn = pk_fma(fg, c, pk_mul(ig, gg));                            \
    const v2f hn = pk_mul(og, tanh2p(pk_mul(cn, two_l2e)));                  \
    if (GUARD) {                                                             \
      const int tl = (S) - g;                                                \
      const bool valid = (unsigned)tl < (unsigned)T_;                        \
      float* wrt = valid ? wrp : trashp;                                     \
      *(v2f*)wrt = hn;                                                       \
      if (valid) c = cn;                                                     \
      if ((g < 5) && (tl == T_ - 1)) {                                       \
        const size_t o1 = (size_t)(B_ * T_) + (size_t)g * (B_ * H_)          \
                          + (size_t)b2 * H_ + j;                             \
        out[o1]      = hn.x;  out[o1 + H_]      = hn.y;                      \
        out[o1 + CO] = cn.x;  out[o1 + CO + H_] = cn.y;                      \
      }                                                                      \
    } else {                                                                 \
      *(v2f*)wrp = hn;                                                       \
      c = cn;                                                                \
    }                                                                        \
    if (OUTST) {                                                             \
      if (doout) outp[(S) - 5] = (j == 0) ? ig.x : ig.y;                     \
    }                                                                        \
    prevp += pinc;                                                           \
  }

// One wave = TWO batch elements (packed {bA,bB} per VGPR pair), all 5 layers
// pipelined across lane-groups (group g = layer g, lane j owns unit j; group 5
// computes the output projection via the uniform gate path). All gate math is
// v_pk_fma_f32 (dual-FP32 pipe): 80 pk-FMAs per TWO cells. No in-loop barriers.
__global__ __launch_bounds__(64, 2)
void lstm5(const float* __restrict__ x,     // [B, T, 2]
           const float* __restrict__ h0,    // [L, B, H]
           const float* __restrict__ c0,    // [L, B, H]
           const float* __restrict__ Wih0,  // [40, 2]
           const float* __restrict__ WihR,  // [4, 40, 10]
           const float* __restrict__ Whh,   // [5, 40, 10]
           const float* __restrict__ bias,  // [5, 40]
           const float* __restrict__ Wf,    // [10]
           const float* __restrict__ bfp,   // [1]
           float* __restrict__ out)         // [B*T] ++ [L*B*H] ++ [L*B*H]
{
    __shared__ __align__(16) float lds[LDS_FLOATS];

    const int lane = threadIdx.x;
    const int g = lane / 10;          // 0..6 (6 = lanes 60-63, idle)
    const int j = lane - g * 10;
    const int b2 = blockIdx.x * 2;    // batch pair {b2, b2+1}
    const size_t CO = (size_t)L_ * B_ * H_;
    const v2f zero2 = (v2f)(0.0f);
    const v2f two_l2e = (v2f){2.0f * LOG2E, 2.0f * LOG2E};

    // ---- stage x for both batches: entry t = {xA0,xB0,xA1,xB1} ----
    {
        const float2* xA2 = (const float2*)(x + (size_t)b2 * (T_ * 2));
        const float2* xB2 = (const float2*)(x + (size_t)(b2 + 1) * (T_ * 2));
        #pragma unroll
        for (int i = 0; i < 8; ++i) {
            const int t = i * 64 + lane;
            const float2 a = xA2[t];
            const float2 bb = xB2[t];
            *(v4f*)&lds[XBUF_F + t * 4] = (v4f){a.x, bb.x, a.y, bb.y};
        }
        if (lane < 8) *(v4f*)&lds[XBUF_F + (512 + lane) * 4] = (v4f)(0.0f);
        if (lane < 32) lds[TRASH_F + lane] = 0.0f;   // trash must be finite
    }

    // ---- weights -> VGPR pairs {w,w} (pre-scaled for exp2) ----
    const float scq[4] = {LOG2E, LOG2E, 2.0f * LOG2E, LOG2E};
    v2f wih2[4][10], whh2[4][10], bs2[4];
    #pragma unroll
    for (int q = 0; q < 4; ++q) {
        bs2[q] = zero2;
        #pragma unroll
        for (int k = 0; k < 10; ++k) { wih2[q][k] = zero2; whh2[q][k] = zero2; }
    }
    if (g < 5) {
        #pragma unroll
        for (int q = 0; q < 4; ++q) {
            const int row = q * H_ + j;
            const float sc = scq[q];
            const float bv = bias[g * 40 + row] * sc;
            bs2[q] = (v2f){bv, bv};
            #pragma unroll
            for (int k = 0; k < 10; ++k) {
                const float w = Whh[g * 400 + row * 10 + k] * sc;
                whh2[q][k] = (v2f){w, w};
            }
            if (g == 0) {
                const float w0 = Wih0[row * 2 + 0] * sc;
                const float w1 = Wih0[row * 2 + 1] * sc;
                wih2[q][0] = (v2f){w0, w0};
                wih2[q][1] = (v2f){w1, w1};
            } else {
                #pragma unroll
                for (int k = 0; k < 10; ++k) {
                    const float w = WihR[(g - 1) * 400 + row * 10 + k] * sc;
                    wih2[q][k] = (v2f){w, w};
                }
            }
        }
    } else if (g == 5) {
        #pragma unroll
        for (int k = 0; k < 10; ++k) {
            const float w = Wf[k] * LOG2E;
            wih2[0][k] = (v2f){w, w};
        }
        const float bv = bfp[0] * LOG2E;
        bs2[0] = (v2f){bv, bv};
    }

    // ---- initial state ----
    v2f c = zero2;
    if (g < 5) {
        const int base = g * (B_ * H_) + b2 * H_ + j;
        c.x = c0[base];
        c.y = c0[base + H_];
        v2f h00;
        h00.x = h0[base];
        h00.y = h0[base + H_];
        *(v2f*)&lds[SLOTF(g) + 2 * j] = h00;
    }
    __syncthreads();   // single wave: effectively free

    // ---- per-lane pointers ----
    float* const slotbase = (g < 5) ? &lds[SLOTF(g)] : &lds[TRASH_F];
    float* ownp  = slotbase;                       // g5/g6: trash (x0 weights)
    float* prevp = (g == 0) ? &lds[XBUF_F]
                 : (g <= 5) ? &lds[SLOTF(g - 1)]
                            : &lds[TRASH_F];
    float* prevp2 = (g == 0 || g > 5) ? &lds[TRASH_F] : prevp + 4;
    float* wrp    = slotbase + 2 * j;
    float* trashp = &lds[TRASH_F] + 2 * (lane & 7);
    const int pinc = (g == 0) ? 4 : 0;             // g0 walks xbuf, 16B/iter

    const bool doout = (g == 5) && (j < 2);
    float* outp = out + (size_t)(b2 + j) * T_;     // only deref'd when doout

    // ---- pipeline: prologue / steady / epilogue ----
    for (int s = 0; s < 5; ++s)        GATES(s, true,  false)
    for (int s = 5; s <= 510; ++s)     GATES(s, false, true )
    for (int s = 511; s <= 516; ++s)   GATES(s, true,  true )
}

extern "C" void kernel_launch(void* const* d_in, const int* in_sizes, int n_in,
                              void* d_out, int out_size, void* d_ws, size_t ws_size,
                              hipStream_t stream) {
    const float* x    = (const float*)d_in[0];
    const float* h0   = (const float*)d_in[1];
    const float* c0   = (const float*)d_in[2];
    const float* Wih0 = (const float*)d_in[3];
    const float* WihR = (const float*)d_in[4];
    const float* Whh  = (const float*)d_in[5];
    const float* bias = (const float*)d_in[6];
    const float* Wf   = (const float*)d_in[7];
    const float* bf   = (const float*)d_in[8];
    float* out = (float*)d_out;

    dim3 grid(B_ / 2);   // 2048 blocks, one wave each, 2 batch elems per wave
    dim3 block(64);
    hipLaunchKernelGGL(lstm5, grid, block, 0, stream,
                       x, h0, c0, Wih0, WihR, Whh, bias, Wf, bf, out);
}